// Round 10
// baseline (281.715 us; speedup 1.0000x reference)
//
#include <hip/hip_runtime.h>

#define N_NODES 50000
#define N_EDGES 800000
#define HEADS 4
#define NUM_GRAPHS 8

#define EBLK ((N_EDGES + 255) / 256)   // 3125
#define NBLK ((N_NODES + 255) / 256)   // 196

// ============ Fused: hist (edge blocks) + fc0/P1 (node blocks) ============
__global__ __launch_bounds__(256) void hist_fc0_kernel(
    const int* __restrict__ dst, int* __restrict__ deg, int* __restrict__ off,
    const float* __restrict__ x,
    const float* __restrict__ fc0_w, const float* __restrict__ fc0_b,
    const float* __restrict__ u1,
    float* __restrict__ h0, float* __restrict__ P1) {
  if (blockIdx.x < EBLK) {
    int e = blockIdx.x * 256 + threadIdx.x;
    if (e < N_EDGES) off[e] = atomicAdd(&deg[dst[e]], 1);
    return;
  }
  __shared__ float sW0[3 * 16];
  __shared__ float sB0[16];
  __shared__ float sU[16 * 4];
  for (int i = threadIdx.x; i < 48; i += 256) sW0[i] = fc0_w[i];
  for (int i = threadIdx.x; i < 16; i += 256) sB0[i] = fc0_b[i];
  for (int i = threadIdx.x; i < 64; i += 256) sU[i] = u1[i];
  __syncthreads();
  int n = (blockIdx.x - EBLK) * 256 + threadIdx.x;
  if (n >= N_NODES) return;
  float x0 = x[n * 3 + 0], x1 = x[n * 3 + 1], x2 = x[n * 3 + 2];
  float h[16];
#pragma unroll
  for (int j = 0; j < 16; j++) {
    float v = x0 * sW0[0 * 16 + j] + x1 * sW0[1 * 16 + j] + x2 * sW0[2 * 16 + j] + sB0[j];
    h[j] = fmaxf(v, 0.f);
    h0[(size_t)n * 16 + j] = h[j];
  }
  float p0 = 0.f, p1 = 0.f, p2 = 0.f, p3 = 0.f;
#pragma unroll
  for (int j = 0; j < 16; j++) {
    p0 += h[j] * sU[j * 4 + 0];
    p1 += h[j] * sU[j * 4 + 1];
    p2 += h[j] * sU[j * 4 + 2];
    p3 += h[j] * sU[j * 4 + 3];
  }
  reinterpret_cast<float4*>(P1)[n] = make_float4(p0, p1, p2, p3);
}

// Wave-aggregated bump allocation.
__global__ __launch_bounds__(256) void alloc_kernel(const int* __restrict__ deg,
                                                    int* __restrict__ gctr,
                                                    int* __restrict__ rowstart) {
  int i = blockIdx.x * blockDim.x + threadIdx.x;
  int lane = threadIdx.x & 63;
  int d = (i < N_NODES) ? deg[i] : 0;
  int pre = d;
#pragma unroll
  for (int offd = 1; offd < 64; offd <<= 1) {
    int v = __shfl_up(pre, offd, 64);
    if (lane >= offd) pre += v;
  }
  int total = __shfl(pre, 63, 64);
  int base = 0;
  if (lane == 63) base = atomicAdd(gctr, total);
  base = __shfl(base, 63, 64);
  if (i < N_NODES) rowstart[i] = base + pre - d;
}

__global__ __launch_bounds__(256) void scatter_kernel(const int* __restrict__ src,
                                                      const int* __restrict__ dst,
                                                      const int* __restrict__ rowstart,
                                                      const int* __restrict__ off,
                                                      int* __restrict__ src_perm) {
  int e = blockIdx.x * blockDim.x + threadIdx.x;
  if (e >= N_EDGES) return;
  src_perm[rowstart[dst[e]] + off[e]] = src[e];
}

__device__ __forceinline__ float4 edge_q(float4 Ps, float b0, float b1, float b2, float b3) {
  float l0 = Ps.x + b0, l1 = Ps.y + b1, l2 = Ps.z + b2, l3 = Ps.w + b3;
  float m = fmaxf(fmaxf(l0, l1), fmaxf(l2, l3));
  float e0 = __expf(l0 - m), e1 = __expf(l1 - m), e2 = __expf(l2 - m), e3 = __expf(l3 - m);
  float inv = 1.f / (e0 + e1 + e2 + e3);
  return make_float4(e0 * inv, e1 * inv, e2 * inv, e3 * inv);
}

// ============ FUSED AGG1 + GEMM1 + P2-proj: wave-per-node, grid-strided ============
// After agg1's shuffle-reduce, lane l holds A[node][l] (l = h*16+cin) — the exact
// GEMM-row operand. Fusing the 64x32 matvec (via per-wave LDS row broadcast)
// eliminates the A[N,64] round-trip and the gemm1 dispatch entirely.
__global__ __launch_bounds__(256) void agg1_gemm1_kernel(
    const int* __restrict__ rowstart, const int* __restrict__ deg,
    const int* __restrict__ src_perm,
    const float* __restrict__ P1, const float* __restrict__ c1,
    const float* __restrict__ h0,
    const float* __restrict__ w1, const float* __restrict__ b1,
    const float* __restrict__ u2,
    float* __restrict__ h1, float* __restrict__ P2) {
  __shared__ float sB[64 * 32];   // permuted W1: sB[k][c], k = h*16+cin
  __shared__ float sU[32 * 4];
  __shared__ float lsA[4][64];
  for (int i = threadIdx.x; i < 64 * 32; i += 256) {
    int hj = i / 32, c = i % 32;
    sB[i] = w1[(hj % 16) * 128 + (hj / 16) * 32 + c];
  }
  for (int i = threadIdx.x; i < 128; i += 256) sU[i] = u2[i];
  __syncthreads();
  int wave = threadIdx.x >> 6;
  int lane = threadIdx.x & 63;
  int g = lane >> 4;
  int j = lane & 15;
  int stripe = (N_NODES + gridDim.x - 1) / gridDim.x;
  int s0 = (int)blockIdx.x * stripe;
  int s1 = min(s0 + stripe, N_NODES);
  const float4* P4 = reinterpret_cast<const float4*>(P1);
  int cc = lane & 31, half = lane >> 5;
  float b1v = b1[cc];
  float u20 = sU[cc * 4 + 0], u21 = sU[cc * 4 + 1], u22 = sU[cc * 4 + 2], u23 = sU[cc * 4 + 3];

  for (int node = s0 + wave; node < s1; node += 4) {
    float4 Pd = P4[node];
    float b0 = c1[0] - Pd.x, b1h = c1[1] - Pd.y, b2h = c1[2] - Pd.z, b3h = c1[3] - Pd.w;
    int e0 = rowstart[node];
    int e1 = e0 + deg[node];
    float a0 = 0.f, a1 = 0.f, a2 = 0.f, a3 = 0.f;
    int p = e0;
    for (; p + 16 <= e1; p += 16) {
      int sA = src_perm[p + 0 + g];
      int sBv = src_perm[p + 4 + g];
      int sC = src_perm[p + 8 + g];
      int sD = src_perm[p + 12 + g];
      float4 PA = P4[sA];
      float4 PB = P4[sBv];
      float4 PC = P4[sC];
      float4 PD = P4[sD];
      float fA = h0[(size_t)sA * 16 + j];
      float fB = h0[(size_t)sBv * 16 + j];
      float fC = h0[(size_t)sC * 16 + j];
      float fD = h0[(size_t)sD * 16 + j];
      float4 qA = edge_q(PA, b0, b1h, b2h, b3h);
      float4 qB = edge_q(PB, b0, b1h, b2h, b3h);
      float4 qC = edge_q(PC, b0, b1h, b2h, b3h);
      float4 qD = edge_q(PD, b0, b1h, b2h, b3h);
      a0 += qA.x * fA + qB.x * fB + qC.x * fC + qD.x * fD;
      a1 += qA.y * fA + qB.y * fB + qC.y * fC + qD.y * fD;
      a2 += qA.z * fA + qB.z * fB + qC.z * fC + qD.z * fD;
      a3 += qA.w * fA + qB.w * fB + qC.w * fC + qD.w * fD;
    }
    for (; p + 4 <= e1; p += 4) {
      int s = src_perm[p + g];
      float4 Ps = P4[s];
      float f = h0[(size_t)s * 16 + j];
      float4 q = edge_q(Ps, b0, b1h, b2h, b3h);
      a0 += q.x * f; a1 += q.y * f; a2 += q.z * f; a3 += q.w * f;
    }
    int rem = e1 - p;
    if (g < rem) {
      int s = src_perm[p + g];
      float4 Ps = P4[s];
      float f = h0[(size_t)s * 16 + j];
      float4 q = edge_q(Ps, b0, b1h, b2h, b3h);
      a0 += q.x * f; a1 += q.y * f; a2 += q.z * f; a3 += q.w * f;
    }
    a0 += __shfl_xor(a0, 16, 64); a0 += __shfl_xor(a0, 32, 64);
    a1 += __shfl_xor(a1, 16, 64); a1 += __shfl_xor(a1, 32, 64);
    a2 += __shfl_xor(a2, 16, 64); a2 += __shfl_xor(a2, 32, 64);
    a3 += __shfl_xor(a3, 16, 64); a3 += __shfl_xor(a3, 32, 64);
    float o = (g == 0) ? a0 : (g == 1) ? a1 : (g == 2) ? a2 : a3;
    // ---- fused GEMM1: h1[node][c] = relu((A·W1)/deg + b1) ----
    lsA[wave][lane] = o;   // same-wave LDS RAW ordered by lgkmcnt
    float inv = 1.f / fmaxf((float)(e1 - e0), 1.f);
    float acc = 0.f;
    const float* ap = &lsA[wave][half * 32];
    const float* bp = &sB[(half * 32) * 32 + cc];
#pragma unroll
    for (int kk = 0; kk < 32; kk++) acc += ap[kk] * bp[kk * 32];
    acc += __shfl_xor(acc, 32, 64);
    float h1v = fmaxf(acc * inv + b1v, 0.f);
    if (half == 0) h1[(size_t)node * 32 + cc] = h1v;
    // ---- fused P2 = relu(h1) · u2 ----
    float hm = (half == 0) ? h1v : 0.f;
    float p0 = hm * u20, p1 = hm * u21, p2 = hm * u22, p3 = hm * u23;
#pragma unroll
    for (int msk = 1; msk < 64; msk <<= 1) {
      p0 += __shfl_xor(p0, msk, 64);
      p1 += __shfl_xor(p1, msk, 64);
      p2 += __shfl_xor(p2, msk, 64);
      p3 += __shfl_xor(p3, msk, 64);
    }
    if (lane == 0) reinterpret_cast<float4*>(P2)[node] = make_float4(p0, p1, p2, p3);
  }
}

// ============ FUSED AGG2 + GEMM2 + POOL: wave-per-node, grid-strided ============
// Lane layout after agg2 reduce: lane holds A[node][g*32+j] and A[node][(g+2)*32+j]
// covering k in [0,128). Per-wave LDS row + 128x64 matvec (lane c owns channel c),
// then pool into per-block LDS accumulators (sorted batch: stripe spans <=2 graphs).
// Eliminates A[N,128] round-trip, gemm2_pool dispatch, and h2 entirely.
__global__ __launch_bounds__(256) void agg2_gemm2_pool_kernel(
    const int* __restrict__ rowstart, const int* __restrict__ deg,
    const int* __restrict__ src_perm,
    const float* __restrict__ P2, const float* __restrict__ c2,
    const float* __restrict__ h1,
    const float* __restrict__ w2, const float* __restrict__ b2,
    const int* __restrict__ batch,
    float* __restrict__ gsum, float* __restrict__ gcnt) {
  __shared__ float sB[128 * 64];  // 32 KB permuted W2: sB[k][c], k = h*32+cin
  __shared__ float lsA[4][128];
  __shared__ float sg[2][64];
  __shared__ float scnt[2];
  __shared__ int sgmin, sgmax;
  for (int i = threadIdx.x; i < 128 * 64; i += 256) {
    int hj = i / 64, c = i % 64;
    sB[i] = w2[(hj % 32) * 256 + (hj / 32) * 64 + c];
  }
  if (threadIdx.x < 128) sg[threadIdx.x >> 6][threadIdx.x & 63] = 0.f;
  if (threadIdx.x < 2) scnt[threadIdx.x] = 0.f;
  int stripe = (N_NODES + gridDim.x - 1) / gridDim.x;
  int s0 = (int)blockIdx.x * stripe;
  int s1 = min(s0 + stripe, N_NODES);
  if (threadIdx.x == 0) {
    int lo = min(s0, N_NODES - 1);
    int hi = min(s1 - 1, N_NODES - 1);
    if (hi < lo) hi = lo;
    sgmin = batch[lo];
    sgmax = batch[hi];
  }
  __syncthreads();
  int wave = threadIdx.x >> 6;
  int lane = threadIdx.x & 63;
  int g = lane >> 5;
  int j = lane & 31;
  int gmin = sgmin;
  const float4* P4 = reinterpret_cast<const float4*>(P2);
  float b2v = b2[lane];

  for (int node = s0 + wave; node < s1; node += 4) {
    float4 Pd = P4[node];
    float b0 = c2[0] - Pd.x, b1h = c2[1] - Pd.y, b2h = c2[2] - Pd.z, b3h = c2[3] - Pd.w;
    int e0 = rowstart[node];
    int e1 = e0 + deg[node];
    float a0 = 0.f, a1 = 0.f, a2 = 0.f, a3 = 0.f;
    int p = e0;
    for (; p + 8 <= e1; p += 8) {
      int sA = src_perm[p + 0 + g];
      int sBv = src_perm[p + 2 + g];
      int sC = src_perm[p + 4 + g];
      int sD = src_perm[p + 6 + g];
      float4 PA = P4[sA];
      float4 PB = P4[sBv];
      float4 PC = P4[sC];
      float4 PD = P4[sD];
      float fA = h1[(size_t)sA * 32 + j];
      float fB = h1[(size_t)sBv * 32 + j];
      float fC = h1[(size_t)sC * 32 + j];
      float fD = h1[(size_t)sD * 32 + j];
      float4 qA = edge_q(PA, b0, b1h, b2h, b3h);
      float4 qB = edge_q(PB, b0, b1h, b2h, b3h);
      float4 qC = edge_q(PC, b0, b1h, b2h, b3h);
      float4 qD = edge_q(PD, b0, b1h, b2h, b3h);
      a0 += qA.x * fA + qB.x * fB + qC.x * fC + qD.x * fD;
      a1 += qA.y * fA + qB.y * fB + qC.y * fC + qD.y * fD;
      a2 += qA.z * fA + qB.z * fB + qC.z * fC + qD.z * fD;
      a3 += qA.w * fA + qB.w * fB + qC.w * fC + qD.w * fD;
    }
    for (; p + 2 <= e1; p += 2) {
      int s = src_perm[p + g];
      float4 Ps = P4[s];
      float f = h1[(size_t)s * 32 + j];
      float4 q = edge_q(Ps, b0, b1h, b2h, b3h);
      a0 += q.x * f; a1 += q.y * f; a2 += q.z * f; a3 += q.w * f;
    }
    int rem = e1 - p;
    if (g < rem) {
      int s = src_perm[p + g];
      float4 Ps = P4[s];
      float f = h1[(size_t)s * 32 + j];
      float4 q = edge_q(Ps, b0, b1h, b2h, b3h);
      a0 += q.x * f; a1 += q.y * f; a2 += q.z * f; a3 += q.w * f;
    }
    a0 += __shfl_xor(a0, 32, 64);
    a1 += __shfl_xor(a1, 32, 64);
    a2 += __shfl_xor(a2, 32, 64);
    a3 += __shfl_xor(a3, 32, 64);
    float oa = (g == 0) ? a0 : a1;
    float ob = (g == 0) ? a2 : a3;
    // ---- fused GEMM2: lane c owns channel c ----
    lsA[wave][g * 32 + j] = oa;         // k = g*32+j
    lsA[wave][(g + 2) * 32 + j] = ob;   // k = (g+2)*32+j
    float acc = 0.f;
    const float* ap = lsA[wave];
    const float* bp = &sB[lane];
#pragma unroll 8
    for (int k = 0; k < 128; k++) acc += ap[k] * bp[k * 64];
    float inv = 1.f / fmaxf((float)(e1 - e0), 1.f);
    float h2v = fmaxf(acc * inv + b2v, 0.f);
    // ---- fused pool ----
    int bv = batch[node];
    int slot = bv - gmin;
    if (slot >= 0 && slot <= 1) {
      atomicAdd(&sg[slot][lane], h2v);
      if (lane == 0) atomicAdd(&scnt[slot], 1.f);
    } else {  // pathological tiny-graph fallback
      atomicAdd(&gsum[bv * 64 + lane], h2v);
      if (lane == 0) atomicAdd(&gcnt[bv], 1.f);
    }
  }
  __syncthreads();
  if (threadIdx.x < 128) {
    int slot = threadIdx.x >> 6, ch = threadIdx.x & 63;
    if (slot == 0 || sgmax > sgmin) {
      int gg = sgmin + slot;
      atomicAdd(&gsum[gg * 64 + ch], sg[slot][ch]);
      if (ch == 0) atomicAdd(&gcnt[gg], scnt[slot]);
    }
  }
}

// ============ Head: out = (gsum/gcnt) @ fc1_w + fc1_b ============
__global__ __launch_bounds__(128) void head_kernel(
    const float* __restrict__ gsum, const float* __restrict__ gcnt,
    const float* __restrict__ fc1_w, const float* __restrict__ fc1_b,
    float* __restrict__ out) {
  int t = threadIdx.x;
  if (t >= NUM_GRAPHS * 10) return;
  int g = t / 10, k = t % 10;
  float inv = 1.f / fmaxf(gcnt[g], 1.f);
  float s = fc1_b[k];
#pragma unroll
  for (int c = 0; c < 64; c++) s += gsum[g * 64 + c] * inv * fc1_w[c * 10 + k];
  out[g * 10 + k] = s;
}

extern "C" void kernel_launch(void* const* d_in, const int* in_sizes, int n_in,
                              void* d_out, int out_size, void* d_ws, size_t ws_size,
                              hipStream_t stream) {
  const float* x = (const float*)d_in[0];
  const int* edge_index = (const int*)d_in[1];
  const int* batch = (const int*)d_in[2];
  const float* fc0_w = (const float*)d_in[3];
  const float* fc0_b = (const float*)d_in[4];
  const float* u1 = (const float*)d_in[5];
  const float* c1 = (const float*)d_in[6];
  const float* w1 = (const float*)d_in[7];
  const float* b1 = (const float*)d_in[8];
  const float* u2 = (const float*)d_in[9];
  const float* c2 = (const float*)d_in[10];
  const float* w2 = (const float*)d_in[11];
  const float* b2 = (const float*)d_in[12];
  const float* fc1_w = (const float*)d_in[13];
  const float* fc1_b = (const float*)d_in[14];
  float* out = (float*)d_out;

  const int* src = edge_index;            // x_j
  const int* dst = edge_index + N_EDGES;  // x_i

  // ---- workspace layout (4-byte words) ----
  // zero region: deg(N) @0, gctr @50000, pad, gsum @50004 (512), gcnt @50516 (8) -> 50524
  char* wsb = (char*)d_ws;
  int* deg = (int*)wsb;                          // N
  int* gctr = deg + N_NODES;                     // 1  @50000
  float* gsum = (float*)wsb + 50004;             // 512
  float* gcnt = gsum + NUM_GRAPHS * 64;          // 8
  int* rowstart = (int*)wsb + 50524;             // N   [50524,100524)
  int* off = rowstart + N_NODES;                 // E   [100524,900524)
  int* src_perm = off + N_EDGES;                 // E   [900524,1700524)
  float* h0 = (float*)wsb + 1700524;             // N*16
  float* h1 = h0 + (size_t)N_NODES * 16;         // N*32
  float* P1 = h1 + (size_t)N_NODES * 32;         // N*4
  float* P2 = P1 + (size_t)N_NODES * 4;          // N*4  (A workspace eliminated)

  (void)hipMemsetAsync(d_ws, 0, 50524 * sizeof(int), stream);

  int nblk = NBLK;
  int eblk = EBLK;

  // hist + fc0/P1 (independent; one grid)
  hist_fc0_kernel<<<eblk + nblk, 256, 0, stream>>>(dst, deg, off, x, fc0_w, fc0_b, u1, h0, P1);
  alloc_kernel<<<nblk, 256, 0, stream>>>(deg, gctr, rowstart);
  scatter_kernel<<<eblk, 256, 0, stream>>>(src, dst, rowstart, off, src_perm);

  // FeaStConv 1 fully fused: agg + GEMM + P2 projection
  agg1_gemm1_kernel<<<2048, 256, 0, stream>>>(rowstart, deg, src_perm, P1, c1, h0,
                                              w1, b1, u2, h1, P2);

  // FeaStConv 2 fully fused: agg + GEMM + pool
  agg2_gemm2_pool_kernel<<<1024, 256, 0, stream>>>(rowstart, deg, src_perm, P2, c2, h1,
                                                   w2, b2, batch, gsum, gcnt);

  head_kernel<<<1, 128, 0, stream>>>(gsum, gcnt, fc1_w, fc1_b, out);
}

// Round 11
// 272.707 us; speedup vs baseline: 1.0330x; 1.0330x over previous
//
#include <hip/hip_runtime.h>

#define N_NODES 50000
#define N_EDGES 800000
#define HEADS 4
#define NUM_GRAPHS 8

#define EBLK ((N_EDGES + 255) / 256)   // 3125
#define NBLK ((N_NODES + 255) / 256)   // 196

// ============ Fused: hist (edge blocks) + fc0/P1/E1 (node blocks) ============
__global__ __launch_bounds__(256) void hist_fc0_kernel(
    const int* __restrict__ dst, int* __restrict__ deg, int* __restrict__ off,
    const float* __restrict__ x,
    const float* __restrict__ fc0_w, const float* __restrict__ fc0_b,
    const float* __restrict__ u1,
    float* __restrict__ h0, float* __restrict__ P1, float* __restrict__ E1) {
  if (blockIdx.x < EBLK) {
    int e = blockIdx.x * 256 + threadIdx.x;
    if (e < N_EDGES) off[e] = atomicAdd(&deg[dst[e]], 1);
    return;
  }
  __shared__ float sW0[3 * 16];
  __shared__ float sB0[16];
  __shared__ float sU[16 * 4];
  for (int i = threadIdx.x; i < 48; i += 256) sW0[i] = fc0_w[i];
  for (int i = threadIdx.x; i < 16; i += 256) sB0[i] = fc0_b[i];
  for (int i = threadIdx.x; i < 64; i += 256) sU[i] = u1[i];
  __syncthreads();
  int n = (blockIdx.x - EBLK) * 256 + threadIdx.x;
  if (n >= N_NODES) return;
  float x0 = x[n * 3 + 0], x1 = x[n * 3 + 1], x2 = x[n * 3 + 2];
  float h[16];
#pragma unroll
  for (int j = 0; j < 16; j++) {
    float v = x0 * sW0[0 * 16 + j] + x1 * sW0[1 * 16 + j] + x2 * sW0[2 * 16 + j] + sB0[j];
    h[j] = fmaxf(v, 0.f);
    h0[(size_t)n * 16 + j] = h[j];
  }
  float p0 = 0.f, p1 = 0.f, p2 = 0.f, p3 = 0.f;
#pragma unroll
  for (int j = 0; j < 16; j++) {
    p0 += h[j] * sU[j * 4 + 0];
    p1 += h[j] * sU[j * 4 + 1];
    p2 += h[j] * sU[j * 4 + 2];
    p3 += h[j] * sU[j * 4 + 3];
  }
  reinterpret_cast<float4*>(P1)[n] = make_float4(p0, p1, p2, p3);
  // E1 = exp(P1): lets edges use exp(Ps+b) = E1[s]*exp(b) — softmax w/o per-edge exp.
  reinterpret_cast<float4*>(E1)[n] =
      make_float4(__expf(p0), __expf(p1), __expf(p2), __expf(p3));
}

// Wave-aggregated bump allocation.
__global__ __launch_bounds__(256) void alloc_kernel(const int* __restrict__ deg,
                                                    int* __restrict__ gctr,
                                                    int* __restrict__ rowstart) {
  int i = blockIdx.x * blockDim.x + threadIdx.x;
  int lane = threadIdx.x & 63;
  int d = (i < N_NODES) ? deg[i] : 0;
  int pre = d;
#pragma unroll
  for (int offd = 1; offd < 64; offd <<= 1) {
    int v = __shfl_up(pre, offd, 64);
    if (lane >= offd) pre += v;
  }
  int total = __shfl(pre, 63, 64);
  int base = 0;
  if (lane == 63) base = atomicAdd(gctr, total);
  base = __shfl(base, 63, 64);
  if (i < N_NODES) rowstart[i] = base + pre - d;
}

__global__ __launch_bounds__(256) void scatter_kernel(const int* __restrict__ src,
                                                      const int* __restrict__ dst,
                                                      const int* __restrict__ rowstart,
                                                      const int* __restrict__ off,
                                                      int* __restrict__ src_perm) {
  int e = blockIdx.x * blockDim.x + threadIdx.x;
  if (e >= N_EDGES) return;
  src_perm[rowstart[dst[e]] + off[e]] = src[e];
}

// softmax weights from factored exponentials: q_h = Es_h*eb_h / sum (no exp, no max)
__device__ __forceinline__ float4 edge_q_fast(float4 Es, float eb0, float eb1,
                                              float eb2, float eb3) {
  float n0 = Es.x * eb0, n1 = Es.y * eb1, n2 = Es.z * eb2, n3 = Es.w * eb3;
  float inv = 1.f / (n0 + n1 + n2 + n3);
  return make_float4(n0 * inv, n1 * inv, n2 * inv, n3 * inv);
}

// ============ FUSED AGG1 + GEMM1 + P2/E2-proj: wave-per-node, grid-strided ============
__global__ __launch_bounds__(256) void agg1_gemm1_kernel(
    const int* __restrict__ rowstart, const int* __restrict__ deg,
    const int* __restrict__ src_perm,
    const float* __restrict__ P1, const float* __restrict__ E1,
    const float* __restrict__ c1,
    const float* __restrict__ h0,
    const float* __restrict__ w1, const float* __restrict__ b1,
    const float* __restrict__ u2,
    float* __restrict__ h1, float* __restrict__ P2, float* __restrict__ E2) {
  __shared__ float sB[64 * 32];   // permuted W1: sB[k][c], k = h*16+cin
  __shared__ float sU[32 * 4];
  __shared__ float lsA[4][64];
  for (int i = threadIdx.x; i < 64 * 32; i += 256) {
    int hj = i / 32, c = i % 32;
    sB[i] = w1[(hj % 16) * 128 + (hj / 16) * 32 + c];
  }
  for (int i = threadIdx.x; i < 128; i += 256) sU[i] = u2[i];
  __syncthreads();
  int wave = threadIdx.x >> 6;
  int lane = threadIdx.x & 63;
  int g = lane >> 4;
  int j = lane & 15;
  int stripe = (N_NODES + gridDim.x - 1) / gridDim.x;
  int s0 = (int)blockIdx.x * stripe;
  int s1 = min(s0 + stripe, N_NODES);
  const float4* P4 = reinterpret_cast<const float4*>(P1);
  const float4* E4 = reinterpret_cast<const float4*>(E1);
  int cc = lane & 31, half = lane >> 5;
  float b1v = b1[cc];
  float u20 = sU[cc * 4 + 0], u21 = sU[cc * 4 + 1], u22 = sU[cc * 4 + 2], u23 = sU[cc * 4 + 3];
  float c10 = c1[0], c11 = c1[1], c12 = c1[2], c13 = c1[3];

  for (int node = s0 + wave; node < s1; node += 4) {
    float4 Pd = P4[node];
    float eb0 = __expf(c10 - Pd.x), eb1 = __expf(c11 - Pd.y);
    float eb2 = __expf(c12 - Pd.z), eb3 = __expf(c13 - Pd.w);
    int e0 = rowstart[node];
    int e1 = e0 + deg[node];
    float a0 = 0.f, a1 = 0.f, a2 = 0.f, a3 = 0.f;
    int p = e0;
    for (; p + 16 <= e1; p += 16) {
      int sA = src_perm[p + 0 + g];
      int sBv = src_perm[p + 4 + g];
      int sC = src_perm[p + 8 + g];
      int sD = src_perm[p + 12 + g];
      float4 EA = E4[sA];
      float4 EB = E4[sBv];
      float4 EC = E4[sC];
      float4 ED = E4[sD];
      float fA = h0[(size_t)sA * 16 + j];
      float fB = h0[(size_t)sBv * 16 + j];
      float fC = h0[(size_t)sC * 16 + j];
      float fD = h0[(size_t)sD * 16 + j];
      float4 qA = edge_q_fast(EA, eb0, eb1, eb2, eb3);
      float4 qB = edge_q_fast(EB, eb0, eb1, eb2, eb3);
      float4 qC = edge_q_fast(EC, eb0, eb1, eb2, eb3);
      float4 qD = edge_q_fast(ED, eb0, eb1, eb2, eb3);
      a0 += qA.x * fA + qB.x * fB + qC.x * fC + qD.x * fD;
      a1 += qA.y * fA + qB.y * fB + qC.y * fC + qD.y * fD;
      a2 += qA.z * fA + qB.z * fB + qC.z * fC + qD.z * fD;
      a3 += qA.w * fA + qB.w * fB + qC.w * fC + qD.w * fD;
    }
    for (; p + 4 <= e1; p += 4) {
      int s = src_perm[p + g];
      float4 Es = E4[s];
      float f = h0[(size_t)s * 16 + j];
      float4 q = edge_q_fast(Es, eb0, eb1, eb2, eb3);
      a0 += q.x * f; a1 += q.y * f; a2 += q.z * f; a3 += q.w * f;
    }
    int rem = e1 - p;
    if (g < rem) {
      int s = src_perm[p + g];
      float4 Es = E4[s];
      float f = h0[(size_t)s * 16 + j];
      float4 q = edge_q_fast(Es, eb0, eb1, eb2, eb3);
      a0 += q.x * f; a1 += q.y * f; a2 += q.z * f; a3 += q.w * f;
    }
    a0 += __shfl_xor(a0, 16, 64); a0 += __shfl_xor(a0, 32, 64);
    a1 += __shfl_xor(a1, 16, 64); a1 += __shfl_xor(a1, 32, 64);
    a2 += __shfl_xor(a2, 16, 64); a2 += __shfl_xor(a2, 32, 64);
    a3 += __shfl_xor(a3, 16, 64); a3 += __shfl_xor(a3, 32, 64);
    float o = (g == 0) ? a0 : (g == 1) ? a1 : (g == 2) ? a2 : a3;
    // ---- fused GEMM1: h1[node][c] = relu((A·W1)/deg + b1) ----
    lsA[wave][lane] = o;   // same-wave LDS RAW ordered by lgkmcnt
    float inv = 1.f / fmaxf((float)(e1 - e0), 1.f);
    float acc = 0.f;
    const float* ap = &lsA[wave][half * 32];
    const float* bp = &sB[(half * 32) * 32 + cc];
#pragma unroll
    for (int kk = 0; kk < 32; kk++) acc += ap[kk] * bp[kk * 32];
    acc += __shfl_xor(acc, 32, 64);
    float h1v = fmaxf(acc * inv + b1v, 0.f);
    if (half == 0) h1[(size_t)node * 32 + cc] = h1v;
    // ---- fused P2 = relu(h1) · u2; E2 = exp(P2) ----
    float hm = (half == 0) ? h1v : 0.f;
    float p0 = hm * u20, p1 = hm * u21, p2 = hm * u22, p3 = hm * u23;
#pragma unroll
    for (int msk = 1; msk < 64; msk <<= 1) {
      p0 += __shfl_xor(p0, msk, 64);
      p1 += __shfl_xor(p1, msk, 64);
      p2 += __shfl_xor(p2, msk, 64);
      p3 += __shfl_xor(p3, msk, 64);
    }
    if (lane == 0) {
      reinterpret_cast<float4*>(P2)[node] = make_float4(p0, p1, p2, p3);
      reinterpret_cast<float4*>(E2)[node] =
          make_float4(__expf(p0), __expf(p1), __expf(p2), __expf(p3));
    }
  }
}

// ============ FUSED AGG2 + GEMM2 + POOL: wave-per-node, grid-strided ============
__global__ __launch_bounds__(256) void agg2_gemm2_pool_kernel(
    const int* __restrict__ rowstart, const int* __restrict__ deg,
    const int* __restrict__ src_perm,
    const float* __restrict__ P2, const float* __restrict__ E2,
    const float* __restrict__ c2,
    const float* __restrict__ h1,
    const float* __restrict__ w2, const float* __restrict__ b2,
    const int* __restrict__ batch,
    float* __restrict__ gsum, float* __restrict__ gcnt) {
  __shared__ float sB[128 * 64];  // 32 KB permuted W2: sB[k][c], k = h*32+cin
  __shared__ float lsA[4][128];
  __shared__ float sg[2][64];
  __shared__ float scnt[2];
  __shared__ int sgmin, sgmax;
  for (int i = threadIdx.x; i < 128 * 64; i += 256) {
    int hj = i / 64, c = i % 64;
    sB[i] = w2[(hj % 32) * 256 + (hj / 32) * 64 + c];
  }
  if (threadIdx.x < 128) sg[threadIdx.x >> 6][threadIdx.x & 63] = 0.f;
  if (threadIdx.x < 2) scnt[threadIdx.x] = 0.f;
  int stripe = (N_NODES + gridDim.x - 1) / gridDim.x;
  int s0 = (int)blockIdx.x * stripe;
  int s1 = min(s0 + stripe, N_NODES);
  if (threadIdx.x == 0) {
    int lo = min(s0, N_NODES - 1);
    int hi = min(s1 - 1, N_NODES - 1);
    if (hi < lo) hi = lo;
    sgmin = batch[lo];
    sgmax = batch[hi];
  }
  __syncthreads();
  int wave = threadIdx.x >> 6;
  int lane = threadIdx.x & 63;
  int g = lane >> 5;
  int j = lane & 31;
  int gmin = sgmin;
  const float4* P4 = reinterpret_cast<const float4*>(P2);
  const float4* E4 = reinterpret_cast<const float4*>(E2);
  float b2v = b2[lane];
  float c20 = c2[0], c21 = c2[1], c22 = c2[2], c23 = c2[3];

  for (int node = s0 + wave; node < s1; node += 4) {
    float4 Pd = P4[node];
    float eb0 = __expf(c20 - Pd.x), eb1 = __expf(c21 - Pd.y);
    float eb2 = __expf(c22 - Pd.z), eb3 = __expf(c23 - Pd.w);
    int e0 = rowstart[node];
    int e1 = e0 + deg[node];
    float a0 = 0.f, a1 = 0.f, a2 = 0.f, a3 = 0.f;
    int p = e0;
    for (; p + 8 <= e1; p += 8) {
      int sA = src_perm[p + 0 + g];
      int sBv = src_perm[p + 2 + g];
      int sC = src_perm[p + 4 + g];
      int sD = src_perm[p + 6 + g];
      float4 EA = E4[sA];
      float4 EB = E4[sBv];
      float4 EC = E4[sC];
      float4 ED = E4[sD];
      float fA = h1[(size_t)sA * 32 + j];
      float fB = h1[(size_t)sBv * 32 + j];
      float fC = h1[(size_t)sC * 32 + j];
      float fD = h1[(size_t)sD * 32 + j];
      float4 qA = edge_q_fast(EA, eb0, eb1, eb2, eb3);
      float4 qB = edge_q_fast(EB, eb0, eb1, eb2, eb3);
      float4 qC = edge_q_fast(EC, eb0, eb1, eb2, eb3);
      float4 qD = edge_q_fast(ED, eb0, eb1, eb2, eb3);
      a0 += qA.x * fA + qB.x * fB + qC.x * fC + qD.x * fD;
      a1 += qA.y * fA + qB.y * fB + qC.y * fC + qD.y * fD;
      a2 += qA.z * fA + qB.z * fB + qC.z * fC + qD.z * fD;
      a3 += qA.w * fA + qB.w * fB + qC.w * fC + qD.w * fD;
    }
    for (; p + 2 <= e1; p += 2) {
      int s = src_perm[p + g];
      float4 Es = E4[s];
      float f = h1[(size_t)s * 32 + j];
      float4 q = edge_q_fast(Es, eb0, eb1, eb2, eb3);
      a0 += q.x * f; a1 += q.y * f; a2 += q.z * f; a3 += q.w * f;
    }
    int rem = e1 - p;
    if (g < rem) {
      int s = src_perm[p + g];
      float4 Es = E4[s];
      float f = h1[(size_t)s * 32 + j];
      float4 q = edge_q_fast(Es, eb0, eb1, eb2, eb3);
      a0 += q.x * f; a1 += q.y * f; a2 += q.z * f; a3 += q.w * f;
    }
    a0 += __shfl_xor(a0, 32, 64);
    a1 += __shfl_xor(a1, 32, 64);
    a2 += __shfl_xor(a2, 32, 64);
    a3 += __shfl_xor(a3, 32, 64);
    float oa = (g == 0) ? a0 : a1;
    float ob = (g == 0) ? a2 : a3;
    // ---- fused GEMM2: lane c owns channel c ----
    lsA[wave][g * 32 + j] = oa;         // k = g*32+j
    lsA[wave][(g + 2) * 32 + j] = ob;   // k = (g+2)*32+j
    float acc = 0.f;
    const float* ap = lsA[wave];
    const float* bp = &sB[lane];
#pragma unroll 8
    for (int k = 0; k < 128; k++) acc += ap[k] * bp[k * 64];
    float inv = 1.f / fmaxf((float)(e1 - e0), 1.f);
    float h2v = fmaxf(acc * inv + b2v, 0.f);
    // ---- fused pool ----
    int bv = batch[node];
    int slot = bv - gmin;
    if (slot >= 0 && slot <= 1) {
      atomicAdd(&sg[slot][lane], h2v);
      if (lane == 0) atomicAdd(&scnt[slot], 1.f);
    } else {  // pathological tiny-graph fallback
      atomicAdd(&gsum[bv * 64 + lane], h2v);
      if (lane == 0) atomicAdd(&gcnt[bv], 1.f);
    }
  }
  __syncthreads();
  if (threadIdx.x < 128) {
    int slot = threadIdx.x >> 6, ch = threadIdx.x & 63;
    if (slot == 0 || sgmax > sgmin) {
      int gg = sgmin + slot;
      atomicAdd(&gsum[gg * 64 + ch], sg[slot][ch]);
      if (ch == 0) atomicAdd(&gcnt[gg], scnt[slot]);
    }
  }
}

// ============ Head: out = (gsum/gcnt) @ fc1_w + fc1_b ============
__global__ __launch_bounds__(128) void head_kernel(
    const float* __restrict__ gsum, const float* __restrict__ gcnt,
    const float* __restrict__ fc1_w, const float* __restrict__ fc1_b,
    float* __restrict__ out) {
  int t = threadIdx.x;
  if (t >= NUM_GRAPHS * 10) return;
  int g = t / 10, k = t % 10;
  float inv = 1.f / fmaxf(gcnt[g], 1.f);
  float s = fc1_b[k];
#pragma unroll
  for (int c = 0; c < 64; c++) s += gsum[g * 64 + c] * inv * fc1_w[c * 10 + k];
  out[g * 10 + k] = s;
}

extern "C" void kernel_launch(void* const* d_in, const int* in_sizes, int n_in,
                              void* d_out, int out_size, void* d_ws, size_t ws_size,
                              hipStream_t stream) {
  const float* x = (const float*)d_in[0];
  const int* edge_index = (const int*)d_in[1];
  const int* batch = (const int*)d_in[2];
  const float* fc0_w = (const float*)d_in[3];
  const float* fc0_b = (const float*)d_in[4];
  const float* u1 = (const float*)d_in[5];
  const float* c1 = (const float*)d_in[6];
  const float* w1 = (const float*)d_in[7];
  const float* b1 = (const float*)d_in[8];
  const float* u2 = (const float*)d_in[9];
  const float* c2 = (const float*)d_in[10];
  const float* w2 = (const float*)d_in[11];
  const float* b2 = (const float*)d_in[12];
  const float* fc1_w = (const float*)d_in[13];
  const float* fc1_b = (const float*)d_in[14];
  float* out = (float*)d_out;

  const int* src = edge_index;            // x_j
  const int* dst = edge_index + N_EDGES;  // x_i

  // ---- workspace layout (4-byte words) ----
  // zero region: deg(N) @0, gctr @50000, pad, gsum @50004 (512), gcnt @50516 (8) -> 50524
  char* wsb = (char*)d_ws;
  int* deg = (int*)wsb;                          // N
  int* gctr = deg + N_NODES;                     // 1  @50000
  float* gsum = (float*)wsb + 50004;             // 512
  float* gcnt = gsum + NUM_GRAPHS * 64;          // 8
  int* rowstart = (int*)wsb + 50524;             // N   [50524,100524)
  int* off = rowstart + N_NODES;                 // E   [100524,900524)
  int* src_perm = off + N_EDGES;                 // E   [900524,1700524)
  float* h0 = (float*)wsb + 1700524;             // N*16
  float* h1 = h0 + (size_t)N_NODES * 16;         // N*32
  float* P1 = h1 + (size_t)N_NODES * 32;         // N*4
  float* P2 = P1 + (size_t)N_NODES * 4;          // N*4
  float* E1 = P2 + (size_t)N_NODES * 4;          // N*4
  float* E2 = E1 + (size_t)N_NODES * 4;          // N*4

  (void)hipMemsetAsync(d_ws, 0, 50524 * sizeof(int), stream);

  int nblk = NBLK;
  int eblk = EBLK;

  // hist + fc0/P1/E1 (independent; one grid)
  hist_fc0_kernel<<<eblk + nblk, 256, 0, stream>>>(dst, deg, off, x, fc0_w, fc0_b, u1,
                                                   h0, P1, E1);
  alloc_kernel<<<nblk, 256, 0, stream>>>(deg, gctr, rowstart);
  scatter_kernel<<<eblk, 256, 0, stream>>>(src, dst, rowstart, off, src_perm);

  // FeaStConv 1 fully fused: agg + GEMM + P2/E2 projection
  agg1_gemm1_kernel<<<2048, 256, 0, stream>>>(rowstart, deg, src_perm, P1, E1, c1, h0,
                                              w1, b1, u2, h1, P2, E2);

  // FeaStConv 2 fully fused: agg + GEMM + pool
  agg2_gemm2_pool_kernel<<<1024, 256, 0, stream>>>(rowstart, deg, src_perm, P2, E2, c2,
                                                   h1, w2, b2, batch, gsum, gcnt);

  head_kernel<<<1, 128, 0, stream>>>(gsum, gcnt, fc1_w, fc1_b, out);
}

// Round 12
// 263.853 us; speedup vs baseline: 1.0677x; 1.0336x over previous
//
#include <hip/hip_runtime.h>

#define N_NODES 50000
#define N_EDGES 800000
#define HEADS 4
#define NUM_GRAPHS 8

#define EBLK ((N_EDGES + 255) / 256)   // 3125
#define NBLK ((N_NODES + 255) / 256)   // 196

// ============ Fused: hist (edge blocks) + fc0/P1/E1 (node blocks) ============
__global__ __launch_bounds__(256) void hist_fc0_kernel(
    const int* __restrict__ dst, int* __restrict__ deg, int* __restrict__ off,
    const float* __restrict__ x,
    const float* __restrict__ fc0_w, const float* __restrict__ fc0_b,
    const float* __restrict__ u1,
    float* __restrict__ h0, float* __restrict__ P1, float* __restrict__ E1) {
  if (blockIdx.x < EBLK) {
    int e = blockIdx.x * 256 + threadIdx.x;
    if (e < N_EDGES) off[e] = atomicAdd(&deg[dst[e]], 1);
    return;
  }
  __shared__ float sW0[3 * 16];
  __shared__ float sB0[16];
  __shared__ float sU[16 * 4];
  for (int i = threadIdx.x; i < 48; i += 256) sW0[i] = fc0_w[i];
  for (int i = threadIdx.x; i < 16; i += 256) sB0[i] = fc0_b[i];
  for (int i = threadIdx.x; i < 64; i += 256) sU[i] = u1[i];
  __syncthreads();
  int n = (blockIdx.x - EBLK) * 256 + threadIdx.x;
  if (n >= N_NODES) return;
  float x0 = x[n * 3 + 0], x1 = x[n * 3 + 1], x2 = x[n * 3 + 2];
  float h[16];
#pragma unroll
  for (int j = 0; j < 16; j++) {
    float v = x0 * sW0[0 * 16 + j] + x1 * sW0[1 * 16 + j] + x2 * sW0[2 * 16 + j] + sB0[j];
    h[j] = fmaxf(v, 0.f);
    h0[(size_t)n * 16 + j] = h[j];
  }
  float p0 = 0.f, p1 = 0.f, p2 = 0.f, p3 = 0.f;
#pragma unroll
  for (int j = 0; j < 16; j++) {
    p0 += h[j] * sU[j * 4 + 0];
    p1 += h[j] * sU[j * 4 + 1];
    p2 += h[j] * sU[j * 4 + 2];
    p3 += h[j] * sU[j * 4 + 3];
  }
  reinterpret_cast<float4*>(P1)[n] = make_float4(p0, p1, p2, p3);
  // E1 = exp(P1): edges use exp(Ps+b) = E1[s]*exp(b) — softmax w/o per-edge exp.
  reinterpret_cast<float4*>(E1)[n] =
      make_float4(__expf(p0), __expf(p1), __expf(p2), __expf(p3));
}

// Wave-aggregated bump allocation.
__global__ __launch_bounds__(256) void alloc_kernel(const int* __restrict__ deg,
                                                    int* __restrict__ gctr,
                                                    int* __restrict__ rowstart) {
  int i = blockIdx.x * blockDim.x + threadIdx.x;
  int lane = threadIdx.x & 63;
  int d = (i < N_NODES) ? deg[i] : 0;
  int pre = d;
#pragma unroll
  for (int offd = 1; offd < 64; offd <<= 1) {
    int v = __shfl_up(pre, offd, 64);
    if (lane >= offd) pre += v;
  }
  int total = __shfl(pre, 63, 64);
  int base = 0;
  if (lane == 63) base = atomicAdd(gctr, total);
  base = __shfl(base, 63, 64);
  if (i < N_NODES) rowstart[i] = base + pre - d;
}

__global__ __launch_bounds__(256) void scatter_kernel(const int* __restrict__ src,
                                                      const int* __restrict__ dst,
                                                      const int* __restrict__ rowstart,
                                                      const int* __restrict__ off,
                                                      int* __restrict__ src_perm) {
  int e = blockIdx.x * blockDim.x + threadIdx.x;
  if (e >= N_EDGES) return;
  src_perm[rowstart[dst[e]] + off[e]] = src[e];
}

// softmax weights from factored exponentials: q_h = Es_h*eb_h / sum (no exp, no max)
__device__ __forceinline__ float4 edge_q_fast(float4 Es, float eb0, float eb1,
                                              float eb2, float eb3) {
  float n0 = Es.x * eb0, n1 = Es.y * eb1, n2 = Es.z * eb2, n3 = Es.w * eb3;
  float inv = 1.f / (n0 + n1 + n2 + n3);
  return make_float4(n0 * inv, n1 * inv, n2 * inv, n3 * inv);
}

// ============ FUSED AGG1 + GEMM1 + P2/E2-proj: wave-per-node, grid-strided ============
// Matvec uses consecutive-quad LDS reads: lane=(r=lane>>3, c4=lane&7) reads
// sB4[(kb+r)*8 + c4] — 64 consecutive float4s per step, conflict-free b128.
// 8 b128 + 8 b32-broadcast per node vs 64+64 scalar reads before.
__global__ __launch_bounds__(256) void agg1_gemm1_kernel(
    const int* __restrict__ rowstart, const int* __restrict__ deg,
    const int* __restrict__ src_perm,
    const float* __restrict__ P1, const float* __restrict__ E1,
    const float* __restrict__ c1,
    const float* __restrict__ h0,
    const float* __restrict__ w1, const float* __restrict__ b1,
    const float* __restrict__ u2,
    float* __restrict__ h1, float* __restrict__ P2, float* __restrict__ E2) {
  __shared__ float sB[64 * 32];   // permuted W1: sB[k][c], k = h*16+cin
  __shared__ float sU[32 * 4];
  __shared__ float lsA[4][64];
  for (int i = threadIdx.x; i < 64 * 32; i += 256) {
    int hj = i / 32, c = i % 32;
    sB[i] = w1[(hj % 16) * 128 + (hj / 16) * 32 + c];
  }
  for (int i = threadIdx.x; i < 128; i += 256) sU[i] = u2[i];
  __syncthreads();
  int wave = threadIdx.x >> 6;
  int lane = threadIdx.x & 63;
  int g = lane >> 4;
  int j = lane & 15;
  int stripe = (N_NODES + gridDim.x - 1) / gridDim.x;
  int s0 = (int)blockIdx.x * stripe;
  int s1 = min(s0 + stripe, N_NODES);
  const float4* P4 = reinterpret_cast<const float4*>(P1);
  const float4* E4 = reinterpret_cast<const float4*>(E1);
  const float4* sB4 = reinterpret_cast<const float4*>(sB);
  int r_off = lane >> 3;   // 0..7
  int c4m = lane & 7;      // 0..7 (channels 4*c4m..4*c4m+3)
  float4 b1q = reinterpret_cast<const float4*>(b1)[c4m];
  float c10 = c1[0], c11 = c1[1], c12 = c1[2], c13 = c1[3];

  for (int node = s0 + wave; node < s1; node += 4) {
    float4 Pd = P4[node];
    float eb0 = __expf(c10 - Pd.x), eb1 = __expf(c11 - Pd.y);
    float eb2 = __expf(c12 - Pd.z), eb3 = __expf(c13 - Pd.w);
    int e0 = rowstart[node];
    int e1 = e0 + deg[node];
    float a0 = 0.f, a1 = 0.f, a2 = 0.f, a3 = 0.f;
    int p = e0;
    for (; p + 16 <= e1; p += 16) {
      int sA = src_perm[p + 0 + g];
      int sBv = src_perm[p + 4 + g];
      int sC = src_perm[p + 8 + g];
      int sD = src_perm[p + 12 + g];
      float4 EA = E4[sA];
      float4 EB = E4[sBv];
      float4 EC = E4[sC];
      float4 ED = E4[sD];
      float fA = h0[(size_t)sA * 16 + j];
      float fB = h0[(size_t)sBv * 16 + j];
      float fC = h0[(size_t)sC * 16 + j];
      float fD = h0[(size_t)sD * 16 + j];
      float4 qA = edge_q_fast(EA, eb0, eb1, eb2, eb3);
      float4 qB = edge_q_fast(EB, eb0, eb1, eb2, eb3);
      float4 qC = edge_q_fast(EC, eb0, eb1, eb2, eb3);
      float4 qD = edge_q_fast(ED, eb0, eb1, eb2, eb3);
      a0 += qA.x * fA + qB.x * fB + qC.x * fC + qD.x * fD;
      a1 += qA.y * fA + qB.y * fB + qC.y * fC + qD.y * fD;
      a2 += qA.z * fA + qB.z * fB + qC.z * fC + qD.z * fD;
      a3 += qA.w * fA + qB.w * fB + qC.w * fC + qD.w * fD;
    }
    for (; p + 4 <= e1; p += 4) {
      int s = src_perm[p + g];
      float4 Es = E4[s];
      float f = h0[(size_t)s * 16 + j];
      float4 q = edge_q_fast(Es, eb0, eb1, eb2, eb3);
      a0 += q.x * f; a1 += q.y * f; a2 += q.z * f; a3 += q.w * f;
    }
    int rem = e1 - p;
    if (g < rem) {
      int s = src_perm[p + g];
      float4 Es = E4[s];
      float f = h0[(size_t)s * 16 + j];
      float4 q = edge_q_fast(Es, eb0, eb1, eb2, eb3);
      a0 += q.x * f; a1 += q.y * f; a2 += q.z * f; a3 += q.w * f;
    }
    a0 += __shfl_xor(a0, 16, 64); a0 += __shfl_xor(a0, 32, 64);
    a1 += __shfl_xor(a1, 16, 64); a1 += __shfl_xor(a1, 32, 64);
    a2 += __shfl_xor(a2, 16, 64); a2 += __shfl_xor(a2, 32, 64);
    a3 += __shfl_xor(a3, 16, 64); a3 += __shfl_xor(a3, 32, 64);
    float o = (g == 0) ? a0 : (g == 1) ? a1 : (g == 2) ? a2 : a3;
    // ---- fused GEMM1 (consecutive-quad matvec) ----
    lsA[wave][lane] = o;   // A[node][lane], lane = h*16+cin
    const float* ap = lsA[wave];
    float4 acc4 = {0.f, 0.f, 0.f, 0.f};
#pragma unroll
    for (int kb = 0; kb < 64; kb += 8) {
      float av = ap[kb + r_off];
      float4 wv = sB4[(size_t)(kb + r_off) * 8 + c4m];
      acc4.x += av * wv.x;
      acc4.y += av * wv.y;
      acc4.z += av * wv.z;
      acc4.w += av * wv.w;
    }
    // reduce over r_off (lane bits 3,4,5)
    acc4.x += __shfl_xor(acc4.x, 8, 64); acc4.x += __shfl_xor(acc4.x, 16, 64); acc4.x += __shfl_xor(acc4.x, 32, 64);
    acc4.y += __shfl_xor(acc4.y, 8, 64); acc4.y += __shfl_xor(acc4.y, 16, 64); acc4.y += __shfl_xor(acc4.y, 32, 64);
    acc4.z += __shfl_xor(acc4.z, 8, 64); acc4.z += __shfl_xor(acc4.z, 16, 64); acc4.z += __shfl_xor(acc4.z, 32, 64);
    acc4.w += __shfl_xor(acc4.w, 8, 64); acc4.w += __shfl_xor(acc4.w, 16, 64); acc4.w += __shfl_xor(acc4.w, 32, 64);
    float inv = 1.f / fmaxf((float)(e1 - e0), 1.f);
    float4 h1v4 = {fmaxf(acc4.x * inv + b1q.x, 0.f), fmaxf(acc4.y * inv + b1q.y, 0.f),
                   fmaxf(acc4.z * inv + b1q.z, 0.f), fmaxf(acc4.w * inv + b1q.w, 0.f)};
    if (r_off == 0) reinterpret_cast<float4*>(h1 + (size_t)node * 32)[c4m] = h1v4;
    // ---- fused P2 = h1 · u2 (every r-replica computes same; reduce over c4m) ----
    int cb = 4 * c4m;
    float p0 = h1v4.x * sU[(cb + 0) * 4 + 0] + h1v4.y * sU[(cb + 1) * 4 + 0] +
               h1v4.z * sU[(cb + 2) * 4 + 0] + h1v4.w * sU[(cb + 3) * 4 + 0];
    float p1 = h1v4.x * sU[(cb + 0) * 4 + 1] + h1v4.y * sU[(cb + 1) * 4 + 1] +
               h1v4.z * sU[(cb + 2) * 4 + 1] + h1v4.w * sU[(cb + 3) * 4 + 1];
    float p2 = h1v4.x * sU[(cb + 0) * 4 + 2] + h1v4.y * sU[(cb + 1) * 4 + 2] +
               h1v4.z * sU[(cb + 2) * 4 + 2] + h1v4.w * sU[(cb + 3) * 4 + 2];
    float p3 = h1v4.x * sU[(cb + 0) * 4 + 3] + h1v4.y * sU[(cb + 1) * 4 + 3] +
               h1v4.z * sU[(cb + 2) * 4 + 3] + h1v4.w * sU[(cb + 3) * 4 + 3];
#pragma unroll
    for (int msk = 1; msk <= 4; msk <<= 1) {
      p0 += __shfl_xor(p0, msk, 64);
      p1 += __shfl_xor(p1, msk, 64);
      p2 += __shfl_xor(p2, msk, 64);
      p3 += __shfl_xor(p3, msk, 64);
    }
    if (lane == 0) {
      reinterpret_cast<float4*>(P2)[node] = make_float4(p0, p1, p2, p3);
      reinterpret_cast<float4*>(E2)[node] =
          make_float4(__expf(p0), __expf(p1), __expf(p2), __expf(p3));
    }
  }
}

// ============ FUSED AGG2 + GEMM2 + POOL: wave-per-node, grid-strided ============
// Matvec: lane=(r=lane>>4, c4=lane&15) reads sB4[(kb+r)*16 + c4] — 64 consecutive
// float4s per step (4 full W2 rows), conflict-free b128. 32 b128 + 32 b32-bcast
// per node vs 128+128 scalar reads before.
__global__ __launch_bounds__(256) void agg2_gemm2_pool_kernel(
    const int* __restrict__ rowstart, const int* __restrict__ deg,
    const int* __restrict__ src_perm,
    const float* __restrict__ P2, const float* __restrict__ E2,
    const float* __restrict__ c2,
    const float* __restrict__ h1,
    const float* __restrict__ w2, const float* __restrict__ b2,
    const int* __restrict__ batch,
    float* __restrict__ gsum, float* __restrict__ gcnt) {
  __shared__ float sB[128 * 64];  // 32 KB permuted W2: sB[k][c], k = h*32+cin
  __shared__ float lsA[4][128];
  __shared__ float sg[2][64];
  __shared__ float scnt[2];
  __shared__ int sgmin, sgmax;
  for (int i = threadIdx.x; i < 128 * 64; i += 256) {
    int hj = i / 64, c = i % 64;
    sB[i] = w2[(hj % 32) * 256 + (hj / 32) * 64 + c];
  }
  if (threadIdx.x < 128) sg[threadIdx.x >> 6][threadIdx.x & 63] = 0.f;
  if (threadIdx.x < 2) scnt[threadIdx.x] = 0.f;
  int stripe = (N_NODES + gridDim.x - 1) / gridDim.x;
  int s0 = (int)blockIdx.x * stripe;
  int s1 = min(s0 + stripe, N_NODES);
  if (threadIdx.x == 0) {
    int lo = min(s0, N_NODES - 1);
    int hi = min(s1 - 1, N_NODES - 1);
    if (hi < lo) hi = lo;
    sgmin = batch[lo];
    sgmax = batch[hi];
  }
  __syncthreads();
  int wave = threadIdx.x >> 6;
  int lane = threadIdx.x & 63;
  int g = lane >> 5;
  int j = lane & 31;
  int gmin = sgmin;
  const float4* P4 = reinterpret_cast<const float4*>(P2);
  const float4* E4 = reinterpret_cast<const float4*>(E2);
  const float4* sB4 = reinterpret_cast<const float4*>(sB);
  int r_off = lane >> 4;   // 0..3
  int c4m = lane & 15;     // 0..15 (channels 4*c4m..4*c4m+3)
  float4 b2q = reinterpret_cast<const float4*>(b2)[c4m];
  float c20 = c2[0], c21 = c2[1], c22 = c2[2], c23 = c2[3];

  for (int node = s0 + wave; node < s1; node += 4) {
    float4 Pd = P4[node];
    float eb0 = __expf(c20 - Pd.x), eb1 = __expf(c21 - Pd.y);
    float eb2 = __expf(c22 - Pd.z), eb3 = __expf(c23 - Pd.w);
    int e0 = rowstart[node];
    int e1 = e0 + deg[node];
    float a0 = 0.f, a1 = 0.f, a2 = 0.f, a3 = 0.f;
    int p = e0;
    for (; p + 8 <= e1; p += 8) {
      int sA = src_perm[p + 0 + g];
      int sBv = src_perm[p + 2 + g];
      int sC = src_perm[p + 4 + g];
      int sD = src_perm[p + 6 + g];
      float4 EA = E4[sA];
      float4 EB = E4[sBv];
      float4 EC = E4[sC];
      float4 ED = E4[sD];
      float fA = h1[(size_t)sA * 32 + j];
      float fB = h1[(size_t)sBv * 32 + j];
      float fC = h1[(size_t)sC * 32 + j];
      float fD = h1[(size_t)sD * 32 + j];
      float4 qA = edge_q_fast(EA, eb0, eb1, eb2, eb3);
      float4 qB = edge_q_fast(EB, eb0, eb1, eb2, eb3);
      float4 qC = edge_q_fast(EC, eb0, eb1, eb2, eb3);
      float4 qD = edge_q_fast(ED, eb0, eb1, eb2, eb3);
      a0 += qA.x * fA + qB.x * fB + qC.x * fC + qD.x * fD;
      a1 += qA.y * fA + qB.y * fB + qC.y * fC + qD.y * fD;
      a2 += qA.z * fA + qB.z * fB + qC.z * fC + qD.z * fD;
      a3 += qA.w * fA + qB.w * fB + qC.w * fC + qD.w * fD;
    }
    for (; p + 2 <= e1; p += 2) {
      int s = src_perm[p + g];
      float4 Es = E4[s];
      float f = h1[(size_t)s * 32 + j];
      float4 q = edge_q_fast(Es, eb0, eb1, eb2, eb3);
      a0 += q.x * f; a1 += q.y * f; a2 += q.z * f; a3 += q.w * f;
    }
    int rem = e1 - p;
    if (g < rem) {
      int s = src_perm[p + g];
      float4 Es = E4[s];
      float f = h1[(size_t)s * 32 + j];
      float4 q = edge_q_fast(Es, eb0, eb1, eb2, eb3);
      a0 += q.x * f; a1 += q.y * f; a2 += q.z * f; a3 += q.w * f;
    }
    a0 += __shfl_xor(a0, 32, 64);
    a1 += __shfl_xor(a1, 32, 64);
    a2 += __shfl_xor(a2, 32, 64);
    a3 += __shfl_xor(a3, 32, 64);
    float oa = (g == 0) ? a0 : a1;
    float ob = (g == 0) ? a2 : a3;
    // ---- fused GEMM2 (consecutive-quad matvec) ----
    lsA[wave][g * 32 + j] = oa;         // k = g*32+j
    lsA[wave][(g + 2) * 32 + j] = ob;   // k = (g+2)*32+j
    const float* ap = lsA[wave];
    float4 acc4 = {0.f, 0.f, 0.f, 0.f};
#pragma unroll 8
    for (int kb = 0; kb < 128; kb += 4) {
      float av = ap[kb + r_off];
      float4 wv = sB4[(size_t)(kb + r_off) * 16 + c4m];
      acc4.x += av * wv.x;
      acc4.y += av * wv.y;
      acc4.z += av * wv.z;
      acc4.w += av * wv.w;
    }
    // reduce over r_off (lane bits 4,5)
    acc4.x += __shfl_xor(acc4.x, 16, 64); acc4.x += __shfl_xor(acc4.x, 32, 64);
    acc4.y += __shfl_xor(acc4.y, 16, 64); acc4.y += __shfl_xor(acc4.y, 32, 64);
    acc4.z += __shfl_xor(acc4.z, 16, 64); acc4.z += __shfl_xor(acc4.z, 32, 64);
    acc4.w += __shfl_xor(acc4.w, 16, 64); acc4.w += __shfl_xor(acc4.w, 32, 64);
    float inv = 1.f / fmaxf((float)(e1 - e0), 1.f);
    float4 h2v4 = {fmaxf(acc4.x * inv + b2q.x, 0.f), fmaxf(acc4.y * inv + b2q.y, 0.f),
                   fmaxf(acc4.z * inv + b2q.z, 0.f), fmaxf(acc4.w * inv + b2q.w, 0.f)};
    // ---- fused pool (r_off==0 lanes own channels 4*c4m..4*c4m+3) ----
    int bv = batch[node];
    int slot = bv - gmin;
    if (r_off == 0) {
      if (slot >= 0 && slot <= 1) {
        atomicAdd(&sg[slot][c4m * 4 + 0], h2v4.x);
        atomicAdd(&sg[slot][c4m * 4 + 1], h2v4.y);
        atomicAdd(&sg[slot][c4m * 4 + 2], h2v4.z);
        atomicAdd(&sg[slot][c4m * 4 + 3], h2v4.w);
        if (lane == 0) atomicAdd(&scnt[slot], 1.f);
      } else {  // pathological tiny-graph fallback
        atomicAdd(&gsum[bv * 64 + c4m * 4 + 0], h2v4.x);
        atomicAdd(&gsum[bv * 64 + c4m * 4 + 1], h2v4.y);
        atomicAdd(&gsum[bv * 64 + c4m * 4 + 2], h2v4.z);
        atomicAdd(&gsum[bv * 64 + c4m * 4 + 3], h2v4.w);
        if (lane == 0) atomicAdd(&gcnt[bv], 1.f);
      }
    }
  }
  __syncthreads();
  if (threadIdx.x < 128) {
    int slot = threadIdx.x >> 6, ch = threadIdx.x & 63;
    if (slot == 0 || sgmax > sgmin) {
      int gg = sgmin + slot;
      atomicAdd(&gsum[gg * 64 + ch], sg[slot][ch]);
      if (ch == 0) atomicAdd(&gcnt[gg], scnt[slot]);
    }
  }
}

// ============ Head: out = (gsum/gcnt) @ fc1_w + fc1_b ============
__global__ __launch_bounds__(128) void head_kernel(
    const float* __restrict__ gsum, const float* __restrict__ gcnt,
    const float* __restrict__ fc1_w, const float* __restrict__ fc1_b,
    float* __restrict__ out) {
  int t = threadIdx.x;
  if (t >= NUM_GRAPHS * 10) return;
  int g = t / 10, k = t % 10;
  float inv = 1.f / fmaxf(gcnt[g], 1.f);
  float s = fc1_b[k];
#pragma unroll
  for (int c = 0; c < 64; c++) s += gsum[g * 64 + c] * inv * fc1_w[c * 10 + k];
  out[g * 10 + k] = s;
}

extern "C" void kernel_launch(void* const* d_in, const int* in_sizes, int n_in,
                              void* d_out, int out_size, void* d_ws, size_t ws_size,
                              hipStream_t stream) {
  const float* x = (const float*)d_in[0];
  const int* edge_index = (const int*)d_in[1];
  const int* batch = (const int*)d_in[2];
  const float* fc0_w = (const float*)d_in[3];
  const float* fc0_b = (const float*)d_in[4];
  const float* u1 = (const float*)d_in[5];
  const float* c1 = (const float*)d_in[6];
  const float* w1 = (const float*)d_in[7];
  const float* b1 = (const float*)d_in[8];
  const float* u2 = (const float*)d_in[9];
  const float* c2 = (const float*)d_in[10];
  const float* w2 = (const float*)d_in[11];
  const float* b2 = (const float*)d_in[12];
  const float* fc1_w = (const float*)d_in[13];
  const float* fc1_b = (const float*)d_in[14];
  float* out = (float*)d_out;

  const int* src = edge_index;            // x_j
  const int* dst = edge_index + N_EDGES;  // x_i

  // ---- workspace layout (4-byte words) ----
  // zero region: deg(N) @0, gctr @50000, pad, gsum @50004 (512), gcnt @50516 (8) -> 50524
  char* wsb = (char*)d_ws;
  int* deg = (int*)wsb;                          // N
  int* gctr = deg + N_NODES;                     // 1  @50000
  float* gsum = (float*)wsb + 50004;             // 512
  float* gcnt = gsum + NUM_GRAPHS * 64;          // 8
  int* rowstart = (int*)wsb + 50524;             // N   [50524,100524)
  int* off = rowstart + N_NODES;                 // E   [100524,900524)
  int* src_perm = off + N_EDGES;                 // E   [900524,1700524)
  float* h0 = (float*)wsb + 1700524;             // N*16
  float* h1 = h0 + (size_t)N_NODES * 16;         // N*32
  float* P1 = h1 + (size_t)N_NODES * 32;         // N*4
  float* P2 = P1 + (size_t)N_NODES * 4;          // N*4
  float* E1 = P2 + (size_t)N_NODES * 4;          // N*4
  float* E2 = E1 + (size_t)N_NODES * 4;          // N*4

  (void)hipMemsetAsync(d_ws, 0, 50524 * sizeof(int), stream);

  int nblk = NBLK;
  int eblk = EBLK;

  // hist + fc0/P1/E1 (independent; one grid)
  hist_fc0_kernel<<<eblk + nblk, 256, 0, stream>>>(dst, deg, off, x, fc0_w, fc0_b, u1,
                                                   h0, P1, E1);
  alloc_kernel<<<nblk, 256, 0, stream>>>(deg, gctr, rowstart);
  scatter_kernel<<<eblk, 256, 0, stream>>>(src, dst, rowstart, off, src_perm);

  // FeaStConv 1 fully fused: agg + GEMM + P2/E2 projection
  agg1_gemm1_kernel<<<2048, 256, 0, stream>>>(rowstart, deg, src_perm, P1, E1, c1, h0,
                                              w1, b1, u2, h1, P2, E2);

  // FeaStConv 2 fully fused: agg + GEMM + pool
  agg2_gemm2_pool_kernel<<<1024, 256, 0, stream>>>(rowstart, deg, src_perm, P2, E2, c2,
                                                   h1, w2, b2, batch, gsum, gcnt);

  head_kernel<<<1, 128, 0, stream>>>(gsum, gcnt, fc1_w, fc1_b, out);
}

// Round 13
// 261.562 us; speedup vs baseline: 1.0771x; 1.0088x over previous
//
#include <hip/hip_runtime.h>

#define N_NODES 50000
#define N_EDGES 800000
#define HEADS 4
#define NUM_GRAPHS 8

#define EBLK ((N_EDGES + 255) / 256)   // 3125
#define NBLK ((N_NODES + 255) / 256)   // 196

// ============ Fused: hist (edge blocks) + fc0/P1/E1 (node blocks) ============
__global__ __launch_bounds__(256) void hist_fc0_kernel(
    const int* __restrict__ dst, int* __restrict__ deg, int* __restrict__ off,
    const float* __restrict__ x,
    const float* __restrict__ fc0_w, const float* __restrict__ fc0_b,
    const float* __restrict__ u1,
    float* __restrict__ h0, float* __restrict__ P1, float* __restrict__ E1) {
  if (blockIdx.x < EBLK) {
    int e = blockIdx.x * 256 + threadIdx.x;
    if (e < N_EDGES) off[e] = atomicAdd(&deg[dst[e]], 1);
    return;
  }
  __shared__ float sW0[3 * 16];
  __shared__ float sB0[16];
  __shared__ float sU[16 * 4];
  for (int i = threadIdx.x; i < 48; i += 256) sW0[i] = fc0_w[i];
  for (int i = threadIdx.x; i < 16; i += 256) sB0[i] = fc0_b[i];
  for (int i = threadIdx.x; i < 64; i += 256) sU[i] = u1[i];
  __syncthreads();
  int n = (blockIdx.x - EBLK) * 256 + threadIdx.x;
  if (n >= N_NODES) return;
  float x0 = x[n * 3 + 0], x1 = x[n * 3 + 1], x2 = x[n * 3 + 2];
  float h[16];
#pragma unroll
  for (int j = 0; j < 16; j++) {
    float v = x0 * sW0[0 * 16 + j] + x1 * sW0[1 * 16 + j] + x2 * sW0[2 * 16 + j] + sB0[j];
    h[j] = fmaxf(v, 0.f);
  }
  float4* h04 = reinterpret_cast<float4*>(h0 + (size_t)n * 16);
  h04[0] = make_float4(h[0], h[1], h[2], h[3]);
  h04[1] = make_float4(h[4], h[5], h[6], h[7]);
  h04[2] = make_float4(h[8], h[9], h[10], h[11]);
  h04[3] = make_float4(h[12], h[13], h[14], h[15]);
  float p0 = 0.f, p1 = 0.f, p2 = 0.f, p3 = 0.f;
#pragma unroll
  for (int j = 0; j < 16; j++) {
    p0 += h[j] * sU[j * 4 + 0];
    p1 += h[j] * sU[j * 4 + 1];
    p2 += h[j] * sU[j * 4 + 2];
    p3 += h[j] * sU[j * 4 + 3];
  }
  reinterpret_cast<float4*>(P1)[n] = make_float4(p0, p1, p2, p3);
  // E1 = exp(P1): edges use exp(Ps+b) = E1[s]*exp(b) — softmax w/o per-edge exp.
  reinterpret_cast<float4*>(E1)[n] =
      make_float4(__expf(p0), __expf(p1), __expf(p2), __expf(p3));
}

// Wave-aggregated bump allocation.
__global__ __launch_bounds__(256) void alloc_kernel(const int* __restrict__ deg,
                                                    int* __restrict__ gctr,
                                                    int* __restrict__ rowstart) {
  int i = blockIdx.x * blockDim.x + threadIdx.x;
  int lane = threadIdx.x & 63;
  int d = (i < N_NODES) ? deg[i] : 0;
  int pre = d;
#pragma unroll
  for (int offd = 1; offd < 64; offd <<= 1) {
    int v = __shfl_up(pre, offd, 64);
    if (lane >= offd) pre += v;
  }
  int total = __shfl(pre, 63, 64);
  int base = 0;
  if (lane == 63) base = atomicAdd(gctr, total);
  base = __shfl(base, 63, 64);
  if (i < N_NODES) rowstart[i] = base + pre - d;
}

__global__ __launch_bounds__(256) void scatter_kernel(const int* __restrict__ src,
                                                      const int* __restrict__ dst,
                                                      const int* __restrict__ rowstart,
                                                      const int* __restrict__ off,
                                                      int* __restrict__ src_perm) {
  int e = blockIdx.x * blockDim.x + threadIdx.x;
  if (e >= N_EDGES) return;
  src_perm[rowstart[dst[e]] + off[e]] = src[e];
}

// softmax weights from factored exponentials: q_h = Es_h*eb_h / sum (no exp, no max)
__device__ __forceinline__ float4 edge_q_fast(float4 Es, float eb0, float eb1,
                                              float eb2, float eb3) {
  float n0 = Es.x * eb0, n1 = Es.y * eb1, n2 = Es.z * eb2, n3 = Es.w * eb3;
  float inv = 1.f / (n0 + n1 + n2 + n3);
  return make_float4(n0 * inv, n1 * inv, n2 * inv, n3 * inv);
}

// ============ FUSED AGG1 + GEMM1 + P2/E2-proj: wave-per-node, grid-strided ============
__global__ __launch_bounds__(256) void agg1_gemm1_kernel(
    const int* __restrict__ rowstart, const int* __restrict__ deg,
    const int* __restrict__ src_perm,
    const float* __restrict__ P1, const float* __restrict__ E1,
    const float* __restrict__ c1,
    const float* __restrict__ h0,
    const float* __restrict__ w1, const float* __restrict__ b1,
    const float* __restrict__ u2,
    float* __restrict__ h1, float* __restrict__ P2, float* __restrict__ E2) {
  __shared__ float sB[64 * 32];   // permuted W1: sB[k][c], k = h*16+cin
  __shared__ float sU[32 * 4];
  __shared__ float lsA[4][64];
  for (int i = threadIdx.x; i < 64 * 32; i += 256) {
    int hj = i / 32, c = i % 32;
    sB[i] = w1[(hj % 16) * 128 + (hj / 16) * 32 + c];
  }
  for (int i = threadIdx.x; i < 128; i += 256) sU[i] = u2[i];
  __syncthreads();
  int wave = threadIdx.x >> 6;
  int lane = threadIdx.x & 63;
  int g = lane >> 4;
  int j = lane & 15;
  int stripe = (N_NODES + gridDim.x - 1) / gridDim.x;
  int s0 = (int)blockIdx.x * stripe;
  int s1 = min(s0 + stripe, N_NODES);
  const float4* P4 = reinterpret_cast<const float4*>(P1);
  const float4* E4 = reinterpret_cast<const float4*>(E1);
  const float4* sB4 = reinterpret_cast<const float4*>(sB);
  int r_off = lane >> 3;   // 0..7
  int c4m = lane & 7;      // 0..7 (channels 4*c4m..4*c4m+3)
  float4 b1q = reinterpret_cast<const float4*>(b1)[c4m];
  float c10 = c1[0], c11 = c1[1], c12 = c1[2], c13 = c1[3];

  for (int node = s0 + wave; node < s1; node += 4) {
    float4 Pd = P4[node];
    float eb0 = __expf(c10 - Pd.x), eb1 = __expf(c11 - Pd.y);
    float eb2 = __expf(c12 - Pd.z), eb3 = __expf(c13 - Pd.w);
    int e0 = rowstart[node];
    int e1 = e0 + deg[node];
    float a0 = 0.f, a1 = 0.f, a2 = 0.f, a3 = 0.f;
    int p = e0;
    for (; p + 16 <= e1; p += 16) {
      int sA = src_perm[p + 0 + g];
      int sBv = src_perm[p + 4 + g];
      int sC = src_perm[p + 8 + g];
      int sD = src_perm[p + 12 + g];
      float4 EA = E4[sA];
      float4 EB = E4[sBv];
      float4 EC = E4[sC];
      float4 ED = E4[sD];
      float fA = h0[(size_t)sA * 16 + j];
      float fB = h0[(size_t)sBv * 16 + j];
      float fC = h0[(size_t)sC * 16 + j];
      float fD = h0[(size_t)sD * 16 + j];
      float4 qA = edge_q_fast(EA, eb0, eb1, eb2, eb3);
      float4 qB = edge_q_fast(EB, eb0, eb1, eb2, eb3);
      float4 qC = edge_q_fast(EC, eb0, eb1, eb2, eb3);
      float4 qD = edge_q_fast(ED, eb0, eb1, eb2, eb3);
      a0 += qA.x * fA + qB.x * fB + qC.x * fC + qD.x * fD;
      a1 += qA.y * fA + qB.y * fB + qC.y * fC + qD.y * fD;
      a2 += qA.z * fA + qB.z * fB + qC.z * fC + qD.z * fD;
      a3 += qA.w * fA + qB.w * fB + qC.w * fC + qD.w * fD;
    }
    for (; p + 4 <= e1; p += 4) {
      int s = src_perm[p + g];
      float4 Es = E4[s];
      float f = h0[(size_t)s * 16 + j];
      float4 q = edge_q_fast(Es, eb0, eb1, eb2, eb3);
      a0 += q.x * f; a1 += q.y * f; a2 += q.z * f; a3 += q.w * f;
    }
    int rem = e1 - p;
    if (g < rem) {
      int s = src_perm[p + g];
      float4 Es = E4[s];
      float f = h0[(size_t)s * 16 + j];
      float4 q = edge_q_fast(Es, eb0, eb1, eb2, eb3);
      a0 += q.x * f; a1 += q.y * f; a2 += q.z * f; a3 += q.w * f;
    }
    a0 += __shfl_xor(a0, 16, 64); a0 += __shfl_xor(a0, 32, 64);
    a1 += __shfl_xor(a1, 16, 64); a1 += __shfl_xor(a1, 32, 64);
    a2 += __shfl_xor(a2, 16, 64); a2 += __shfl_xor(a2, 32, 64);
    a3 += __shfl_xor(a3, 16, 64); a3 += __shfl_xor(a3, 32, 64);
    float o = (g == 0) ? a0 : (g == 1) ? a1 : (g == 2) ? a2 : a3;
    // ---- fused GEMM1 (consecutive-quad matvec) ----
    lsA[wave][lane] = o;   // A[node][lane], lane = h*16+cin
    const float* ap = lsA[wave];
    float4 acc4 = {0.f, 0.f, 0.f, 0.f};
#pragma unroll
    for (int kb = 0; kb < 64; kb += 8) {
      float av = ap[kb + r_off];
      float4 wv = sB4[(size_t)(kb + r_off) * 8 + c4m];
      acc4.x += av * wv.x;
      acc4.y += av * wv.y;
      acc4.z += av * wv.z;
      acc4.w += av * wv.w;
    }
    // reduce over r_off (lane bits 3,4,5)
    acc4.x += __shfl_xor(acc4.x, 8, 64); acc4.x += __shfl_xor(acc4.x, 16, 64); acc4.x += __shfl_xor(acc4.x, 32, 64);
    acc4.y += __shfl_xor(acc4.y, 8, 64); acc4.y += __shfl_xor(acc4.y, 16, 64); acc4.y += __shfl_xor(acc4.y, 32, 64);
    acc4.z += __shfl_xor(acc4.z, 8, 64); acc4.z += __shfl_xor(acc4.z, 16, 64); acc4.z += __shfl_xor(acc4.z, 32, 64);
    acc4.w += __shfl_xor(acc4.w, 8, 64); acc4.w += __shfl_xor(acc4.w, 16, 64); acc4.w += __shfl_xor(acc4.w, 32, 64);
    float inv = 1.f / fmaxf((float)(e1 - e0), 1.f);
    float4 h1v4 = {fmaxf(acc4.x * inv + b1q.x, 0.f), fmaxf(acc4.y * inv + b1q.y, 0.f),
                   fmaxf(acc4.z * inv + b1q.z, 0.f), fmaxf(acc4.w * inv + b1q.w, 0.f)};
    if (r_off == 0) reinterpret_cast<float4*>(h1 + (size_t)node * 32)[c4m] = h1v4;
    // ---- fused P2 = h1 · u2 (every r-replica computes same; reduce over c4m) ----
    int cb = 4 * c4m;
    float p0 = h1v4.x * sU[(cb + 0) * 4 + 0] + h1v4.y * sU[(cb + 1) * 4 + 0] +
               h1v4.z * sU[(cb + 2) * 4 + 0] + h1v4.w * sU[(cb + 3) * 4 + 0];
    float p1 = h1v4.x * sU[(cb + 0) * 4 + 1] + h1v4.y * sU[(cb + 1) * 4 + 1] +
               h1v4.z * sU[(cb + 2) * 4 + 1] + h1v4.w * sU[(cb + 3) * 4 + 1];
    float p2 = h1v4.x * sU[(cb + 0) * 4 + 2] + h1v4.y * sU[(cb + 1) * 4 + 2] +
               h1v4.z * sU[(cb + 2) * 4 + 2] + h1v4.w * sU[(cb + 3) * 4 + 2];
    float p3 = h1v4.x * sU[(cb + 0) * 4 + 3] + h1v4.y * sU[(cb + 1) * 4 + 3] +
               h1v4.z * sU[(cb + 2) * 4 + 3] + h1v4.w * sU[(cb + 3) * 4 + 3];
#pragma unroll
    for (int msk = 1; msk <= 4; msk <<= 1) {
      p0 += __shfl_xor(p0, msk, 64);
      p1 += __shfl_xor(p1, msk, 64);
      p2 += __shfl_xor(p2, msk, 64);
      p3 += __shfl_xor(p3, msk, 64);
    }
    if (lane == 0) {
      reinterpret_cast<float4*>(P2)[node] = make_float4(p0, p1, p2, p3);
      reinterpret_cast<float4*>(E2)[node] =
          make_float4(__expf(p0), __expf(p1), __expf(p2), __expf(p3));
    }
  }
}

// ============ FUSED AGG2 + GEMM2 + POOL: wave-per-node, grid-strided ============
// 16-edge main loop: 8 E-gathers + 8 h-gathers in flight per iteration (2x the
// r12 window) — halves exposed L2 latency at fixed occupancy (LDS caps 4 blk/CU).
__global__ __launch_bounds__(256) void agg2_gemm2_pool_kernel(
    const int* __restrict__ rowstart, const int* __restrict__ deg,
    const int* __restrict__ src_perm,
    const float* __restrict__ P2, const float* __restrict__ E2,
    const float* __restrict__ c2,
    const float* __restrict__ h1,
    const float* __restrict__ w2, const float* __restrict__ b2,
    const int* __restrict__ batch,
    float* __restrict__ gsum, float* __restrict__ gcnt) {
  __shared__ float sB[128 * 64];  // 32 KB permuted W2: sB[k][c], k = h*32+cin
  __shared__ float lsA[4][128];
  __shared__ float sg[2][64];
  __shared__ float scnt[2];
  __shared__ int sgmin, sgmax;
  for (int i = threadIdx.x; i < 128 * 64; i += 256) {
    int hj = i / 64, c = i % 64;
    sB[i] = w2[(hj % 32) * 256 + (hj / 32) * 64 + c];
  }
  if (threadIdx.x < 128) sg[threadIdx.x >> 6][threadIdx.x & 63] = 0.f;
  if (threadIdx.x < 2) scnt[threadIdx.x] = 0.f;
  int stripe = (N_NODES + gridDim.x - 1) / gridDim.x;
  int s0 = (int)blockIdx.x * stripe;
  int s1 = min(s0 + stripe, N_NODES);
  if (threadIdx.x == 0) {
    int lo = min(s0, N_NODES - 1);
    int hi = min(s1 - 1, N_NODES - 1);
    if (hi < lo) hi = lo;
    sgmin = batch[lo];
    sgmax = batch[hi];
  }
  __syncthreads();
  int wave = threadIdx.x >> 6;
  int lane = threadIdx.x & 63;
  int g = lane >> 5;
  int j = lane & 31;
  int gmin = sgmin;
  const float4* P4 = reinterpret_cast<const float4*>(P2);
  const float4* E4 = reinterpret_cast<const float4*>(E2);
  const float4* sB4 = reinterpret_cast<const float4*>(sB);
  int r_off = lane >> 4;   // 0..3
  int c4m = lane & 15;     // 0..15 (channels 4*c4m..4*c4m+3)
  float4 b2q = reinterpret_cast<const float4*>(b2)[c4m];
  float c20 = c2[0], c21 = c2[1], c22 = c2[2], c23 = c2[3];

  for (int node = s0 + wave; node < s1; node += 4) {
    float4 Pd = P4[node];
    float eb0 = __expf(c20 - Pd.x), eb1 = __expf(c21 - Pd.y);
    float eb2 = __expf(c22 - Pd.z), eb3 = __expf(c23 - Pd.w);
    int e0 = rowstart[node];
    int e1 = e0 + deg[node];
    float a0 = 0.f, a1 = 0.f, a2 = 0.f, a3 = 0.f;
    int p = e0;
    // ---- 16-edge main loop: 8 edges per g-group, 16 gathers in flight ----
    for (; p + 16 <= e1; p += 16) {
      int seA = src_perm[p + 0 + g];
      int seB = src_perm[p + 2 + g];
      int seC = src_perm[p + 4 + g];
      int seD = src_perm[p + 6 + g];
      int seE = src_perm[p + 8 + g];
      int seF = src_perm[p + 10 + g];
      int seG = src_perm[p + 12 + g];
      int seH = src_perm[p + 14 + g];
      float4 EA = E4[seA];
      float4 EB = E4[seB];
      float4 EC = E4[seC];
      float4 ED = E4[seD];
      float4 EE = E4[seE];
      float4 EF = E4[seF];
      float4 EG = E4[seG];
      float4 EH = E4[seH];
      float fA = h1[(size_t)seA * 32 + j];
      float fB = h1[(size_t)seB * 32 + j];
      float fC = h1[(size_t)seC * 32 + j];
      float fD = h1[(size_t)seD * 32 + j];
      float fE = h1[(size_t)seE * 32 + j];
      float fF = h1[(size_t)seF * 32 + j];
      float fG = h1[(size_t)seG * 32 + j];
      float fH = h1[(size_t)seH * 32 + j];
      float4 qA = edge_q_fast(EA, eb0, eb1, eb2, eb3);
      float4 qB = edge_q_fast(EB, eb0, eb1, eb2, eb3);
      float4 qC = edge_q_fast(EC, eb0, eb1, eb2, eb3);
      float4 qD = edge_q_fast(ED, eb0, eb1, eb2, eb3);
      float4 qE = edge_q_fast(EE, eb0, eb1, eb2, eb3);
      float4 qF = edge_q_fast(EF, eb0, eb1, eb2, eb3);
      float4 qG = edge_q_fast(EG, eb0, eb1, eb2, eb3);
      float4 qH = edge_q_fast(EH, eb0, eb1, eb2, eb3);
      a0 += qA.x * fA + qB.x * fB + qC.x * fC + qD.x * fD +
            qE.x * fE + qF.x * fF + qG.x * fG + qH.x * fH;
      a1 += qA.y * fA + qB.y * fB + qC.y * fC + qD.y * fD +
            qE.y * fE + qF.y * fF + qG.y * fG + qH.y * fH;
      a2 += qA.z * fA + qB.z * fB + qC.z * fC + qD.z * fD +
            qE.z * fE + qF.z * fF + qG.z * fG + qH.z * fH;
      a3 += qA.w * fA + qB.w * fB + qC.w * fC + qD.w * fD +
            qE.w * fE + qF.w * fF + qG.w * fG + qH.w * fH;
    }
    for (; p + 8 <= e1; p += 8) {
      int seA = src_perm[p + 0 + g];
      int seB = src_perm[p + 2 + g];
      int seC = src_perm[p + 4 + g];
      int seD = src_perm[p + 6 + g];
      float4 EA = E4[seA];
      float4 EB = E4[seB];
      float4 EC = E4[seC];
      float4 ED = E4[seD];
      float fA = h1[(size_t)seA * 32 + j];
      float fB = h1[(size_t)seB * 32 + j];
      float fC = h1[(size_t)seC * 32 + j];
      float fD = h1[(size_t)seD * 32 + j];
      float4 qA = edge_q_fast(EA, eb0, eb1, eb2, eb3);
      float4 qB = edge_q_fast(EB, eb0, eb1, eb2, eb3);
      float4 qC = edge_q_fast(EC, eb0, eb1, eb2, eb3);
      float4 qD = edge_q_fast(ED, eb0, eb1, eb2, eb3);
      a0 += qA.x * fA + qB.x * fB + qC.x * fC + qD.x * fD;
      a1 += qA.y * fA + qB.y * fB + qC.y * fC + qD.y * fD;
      a2 += qA.z * fA + qB.z * fB + qC.z * fC + qD.z * fD;
      a3 += qA.w * fA + qB.w * fB + qC.w * fC + qD.w * fD;
    }
    for (; p + 2 <= e1; p += 2) {
      int s = src_perm[p + g];
      float4 Es = E4[s];
      float f = h1[(size_t)s * 32 + j];
      float4 q = edge_q_fast(Es, eb0, eb1, eb2, eb3);
      a0 += q.x * f; a1 += q.y * f; a2 += q.z * f; a3 += q.w * f;
    }
    int rem = e1 - p;
    if (g < rem) {
      int s = src_perm[p + g];
      float4 Es = E4[s];
      float f = h1[(size_t)s * 32 + j];
      float4 q = edge_q_fast(Es, eb0, eb1, eb2, eb3);
      a0 += q.x * f; a1 += q.y * f; a2 += q.z * f; a3 += q.w * f;
    }
    a0 += __shfl_xor(a0, 32, 64);
    a1 += __shfl_xor(a1, 32, 64);
    a2 += __shfl_xor(a2, 32, 64);
    a3 += __shfl_xor(a3, 32, 64);
    float oa = (g == 0) ? a0 : a1;
    float ob = (g == 0) ? a2 : a3;
    // ---- fused GEMM2 (consecutive-quad matvec) ----
    lsA[wave][g * 32 + j] = oa;         // k = g*32+j
    lsA[wave][(g + 2) * 32 + j] = ob;   // k = (g+2)*32+j
    const float* ap = lsA[wave];
    float4 acc4 = {0.f, 0.f, 0.f, 0.f};
#pragma unroll 8
    for (int kb = 0; kb < 128; kb += 4) {
      float av = ap[kb + r_off];
      float4 wv = sB4[(size_t)(kb + r_off) * 16 + c4m];
      acc4.x += av * wv.x;
      acc4.y += av * wv.y;
      acc4.z += av * wv.z;
      acc4.w += av * wv.w;
    }
    // reduce over r_off (lane bits 4,5)
    acc4.x += __shfl_xor(acc4.x, 16, 64); acc4.x += __shfl_xor(acc4.x, 32, 64);
    acc4.y += __shfl_xor(acc4.y, 16, 64); acc4.y += __shfl_xor(acc4.y, 32, 64);
    acc4.z += __shfl_xor(acc4.z, 16, 64); acc4.z += __shfl_xor(acc4.z, 32, 64);
    acc4.w += __shfl_xor(acc4.w, 16, 64); acc4.w += __shfl_xor(acc4.w, 32, 64);
    float inv = 1.f / fmaxf((float)(e1 - e0), 1.f);
    float4 h2v4 = {fmaxf(acc4.x * inv + b2q.x, 0.f), fmaxf(acc4.y * inv + b2q.y, 0.f),
                   fmaxf(acc4.z * inv + b2q.z, 0.f), fmaxf(acc4.w * inv + b2q.w, 0.f)};
    // ---- fused pool (r_off==0 lanes own channels 4*c4m..4*c4m+3) ----
    int bv = batch[node];
    int slot = bv - gmin;
    if (r_off == 0) {
      if (slot >= 0 && slot <= 1) {
        atomicAdd(&sg[slot][c4m * 4 + 0], h2v4.x);
        atomicAdd(&sg[slot][c4m * 4 + 1], h2v4.y);
        atomicAdd(&sg[slot][c4m * 4 + 2], h2v4.z);
        atomicAdd(&sg[slot][c4m * 4 + 3], h2v4.w);
        if (lane == 0) atomicAdd(&scnt[slot], 1.f);
      } else {  // pathological tiny-graph fallback
        atomicAdd(&gsum[bv * 64 + c4m * 4 + 0], h2v4.x);
        atomicAdd(&gsum[bv * 64 + c4m * 4 + 1], h2v4.y);
        atomicAdd(&gsum[bv * 64 + c4m * 4 + 2], h2v4.z);
        atomicAdd(&gsum[bv * 64 + c4m * 4 + 3], h2v4.w);
        if (lane == 0) atomicAdd(&gcnt[bv], 1.f);
      }
    }
  }
  __syncthreads();
  if (threadIdx.x < 128) {
    int slot = threadIdx.x >> 6, ch = threadIdx.x & 63;
    if (slot == 0 || sgmax > sgmin) {
      int gg = sgmin + slot;
      atomicAdd(&gsum[gg * 64 + ch], sg[slot][ch]);
      if (ch == 0) atomicAdd(&gcnt[gg], scnt[slot]);
    }
  }
}

// ============ Head: out = (gsum/gcnt) @ fc1_w + fc1_b ============
__global__ __launch_bounds__(128) void head_kernel(
    const float* __restrict__ gsum, const float* __restrict__ gcnt,
    const float* __restrict__ fc1_w, const float* __restrict__ fc1_b,
    float* __restrict__ out) {
  int t = threadIdx.x;
  if (t >= NUM_GRAPHS * 10) return;
  int g = t / 10, k = t % 10;
  float inv = 1.f / fmaxf(gcnt[g], 1.f);
  float s = fc1_b[k];
#pragma unroll
  for (int c = 0; c < 64; c++) s += gsum[g * 64 + c] * inv * fc1_w[c * 10 + k];
  out[g * 10 + k] = s;
}

extern "C" void kernel_launch(void* const* d_in, const int* in_sizes, int n_in,
                              void* d_out, int out_size, void* d_ws, size_t ws_size,
                              hipStream_t stream) {
  const float* x = (const float*)d_in[0];
  const int* edge_index = (const int*)d_in[1];
  const int* batch = (const int*)d_in[2];
  const float* fc0_w = (const float*)d_in[3];
  const float* fc0_b = (const float*)d_in[4];
  const float* u1 = (const float*)d_in[5];
  const float* c1 = (const float*)d_in[6];
  const float* w1 = (const float*)d_in[7];
  const float* b1 = (const float*)d_in[8];
  const float* u2 = (const float*)d_in[9];
  const float* c2 = (const float*)d_in[10];
  const float* w2 = (const float*)d_in[11];
  const float* b2 = (const float*)d_in[12];
  const float* fc1_w = (const float*)d_in[13];
  const float* fc1_b = (const float*)d_in[14];
  float* out = (float*)d_out;

  const int* src = edge_index;            // x_j
  const int* dst = edge_index + N_EDGES;  // x_i

  // ---- workspace layout (4-byte words) ----
  // zero region: deg(N) @0, gctr @50000, pad, gsum @50004 (512), gcnt @50516 (8) -> 50524
  char* wsb = (char*)d_ws;
  int* deg = (int*)wsb;                          // N
  int* gctr = deg + N_NODES;                     // 1  @50000
  float* gsum = (float*)wsb + 50004;             // 512
  float* gcnt = gsum + NUM_GRAPHS * 64;          // 8
  int* rowstart = (int*)wsb + 50524;             // N   [50524,100524)
  int* off = rowstart + N_NODES;                 // E   [100524,900524)
  int* src_perm = off + N_EDGES;                 // E   [900524,1700524)
  float* h0 = (float*)wsb + 1700524;             // N*16
  float* h1 = h0 + (size_t)N_NODES * 16;         // N*32
  float* P1 = h1 + (size_t)N_NODES * 32;         // N*4
  float* P2 = P1 + (size_t)N_NODES * 4;          // N*4
  float* E1 = P2 + (size_t)N_NODES * 4;          // N*4
  float* E2 = E1 + (size_t)N_NODES * 4;          // N*4

  (void)hipMemsetAsync(d_ws, 0, 50524 * sizeof(int), stream);

  int nblk = NBLK;
  int eblk = EBLK;

  // hist + fc0/P1/E1 (independent; one grid)
  hist_fc0_kernel<<<eblk + nblk, 256, 0, stream>>>(dst, deg, off, x, fc0_w, fc0_b, u1,
                                                   h0, P1, E1);
  alloc_kernel<<<nblk, 256, 0, stream>>>(deg, gctr, rowstart);
  scatter_kernel<<<eblk, 256, 0, stream>>>(src, dst, rowstart, off, src_perm);

  // FeaStConv 1 fully fused: agg + GEMM + P2/E2 projection
  agg1_gemm1_kernel<<<2048, 256, 0, stream>>>(rowstart, deg, src_perm, P1, E1, c1, h0,
                                              w1, b1, u2, h1, P2, E2);

  // FeaStConv 2 fully fused: agg + GEMM + pool
  agg2_gemm2_pool_kernel<<<1024, 256, 0, stream>>>(rowstart, deg, src_perm, P2, E2, c2,
                                                   h1, w2, b2, batch, gsum, gcnt);

  head_kernel<<<1, 128, 0, stream>>>(gsum, gcnt, fc1_w, fc1_b, out);
}